// Round 1
// baseline (263.512 us; speedup 1.0000x reference)
//
#include <hip/hip_runtime.h>
#include <math.h>

typedef __bf16 bf16x8 __attribute__((ext_vector_type(8)));
typedef float f32x4 __attribute__((ext_vector_type(4)));
typedef unsigned short u16x8 __attribute__((ext_vector_type(8)));
typedef unsigned short u16x4v __attribute__((ext_vector_type(4)));

constexpr int NIMG = 16384;   // H*W
constexpr int HPITCH = 130;   // padded row pitch (tokens) for g_h
constexpr int HROW = HPITCH*256; // shorts per padded image row

__device__ __forceinline__ unsigned short f2bf(float f){
  unsigned u = __builtin_bit_cast(unsigned, f);
  u += 0x7fffu + ((u>>16)&1u);
  return (unsigned short)(u>>16);
}
__device__ __forceinline__ unsigned pack2(float a, float b){
  return (unsigned)f2bf(a) | ((unsigned)f2bf(b)<<16);
}
__device__ __forceinline__ float bf2f(unsigned short h){
  unsigned u = ((unsigned)h)<<16;
  return __builtin_bit_cast(float, u);
}
__device__ __forceinline__ bf16x8 ldfrag_g(const unsigned short* p){
  u16x8 v = *reinterpret_cast<const u16x8*>(p);
  return __builtin_bit_cast(bf16x8, v);
}
__device__ __forceinline__ f32x4 mfma16(bf16x8 a, bf16x8 b, f32x4 c){
  return __builtin_amdgcn_mfma_f32_16x16x32_bf16(a, b, c, 0, 0, 0);
}
__device__ __forceinline__ f32x4 bfcvt4(uint2 q){
  f32x4 r;
  r[0] = __builtin_bit_cast(float, q.x << 16);
  r[1] = __builtin_bit_cast(float, q.x & 0xffff0000u);
  r[2] = __builtin_bit_cast(float, q.y << 16);
  r[3] = __builtin_bit_cast(float, q.y & 0xffff0000u);
  return r;
}

// ============ k0: weights fp32 -> bf16 MFMA fragment layout (+ tap repack) ============
__global__ __launch_bounds__(64) void k0_wfrag(
  const float* __restrict__ Wk, const float* __restrict__ Wq,
  const float* __restrict__ Wv, const float* __restrict__ Wr,
  const float* __restrict__ W1, const float* __restrict__ W2,
  const float* __restrict__ dww, float* __restrict__ dwp,
  unsigned short* __restrict__ wf)
{
  const int bid = blockIdx.x, l = threadIdx.x;
  if (bid == 96){
    // repack taps: dwp[group g=0..63][tap j=0..8][ch c=0..3] ; channel f = g*4+c
    #pragma unroll
    for (int c=0;c<4;++c){
      int f = l*4 + c;
      #pragma unroll
      for (int j=0;j<9;++j) dwp[l*36 + j*4 + c] = dww[f*9+j];
    }
    return;
  }
  const float* src; int K, nt, ks; unsigned short* dst;
  if (bid < 32){
    int w = bid>>3, f = bid&7;
    src = (w==0)?Wk:(w==1)?Wq:(w==2)?Wv:Wr;
    K = 64; nt = f>>1; ks = f&1;
    dst = wf + w*4096 + f*512;
  } else if (bid < 64){
    int f = bid-32; src = W1; K = 64; nt = f>>1; ks = f&1;
    dst = wf + 16384 + f*512;
  } else {
    int f = bid-64; src = W2; K = 256; nt = f>>3; ks = f&7;
    dst = wf + 32768 + f*512;
  }
  u16x8 v;
  #pragma unroll
  for (int j=0;j<8;++j){
    int k = ks*32 + (l>>4)*8 + j;
    int n = nt*16 + (l&15);
    v[j] = f2bf(src[n*K + k]);
  }
  *reinterpret_cast<u16x8*>(dst + l*8) = v;
}

// ============ zhalo: zero g_h halo columns + shared zero-row ============
__global__ __launch_bounds__(256) void zhalo(unsigned* __restrict__ gh, unsigned* __restrict__ zr){
  int idx = blockIdx.x*256 + threadIdx.x;
  if (idx < 524288){
    int ch2 = idx & 127;
    int pos = idx >> 7;
    int side = pos & 1, row = pos >> 1;
    gh[(size_t)(row*HPITCH + side*(HPITCH-1))*128 + ch2] = 0;
  } else {
    int j = idx - 524288;
    if (j < HROW/2) zr[j] = 0;
  }
}

// ============ k1: LN1 + K/V proj (MFMA) + ctx accumulation (MFMA, LDS-transpose) ============
__global__ __launch_bounds__(256,2) void k1_ctx(
  const float* __restrict__ x, const float* __restrict__ g1, const float* __restrict__ be1,
  const float* __restrict__ bk, const float* __restrict__ bv,
  const unsigned short* __restrict__ wf,
  float* __restrict__ g_part, float* __restrict__ g_sump)
{
  __shared__ unsigned short tiles[4][4096];
  __shared__ float ctx_l[64*68];
  __shared__ float ssum_l[4][64];
  const int t = threadIdx.x, wid = t>>6, l = t&63;
  const int lg = l>>4, l15 = l&15;
  unsigned short* tile = tiles[wid];
  const int tok0 = blockIdx.x*512 + wid*128;

  bf16x8 WkF[8], WvF[8];
  #pragma unroll
  for (int f=0; f<8; ++f){
    WkF[f] = ldfrag_g(wf +    0 + f*512 + l*8);
    WvF[f] = ldfrag_g(wf + 8192 + f*512 + l*8);
  }
  float4 g1v  = *reinterpret_cast<const float4*>(&g1[l15*4]);
  float4 be1v = *reinterpret_cast<const float4*>(&be1[l15*4]);
  float bkv[4], bvv[4];
  #pragma unroll
  for (int ct=0; ct<4; ++ct){ bkv[ct]=bk[ct*16+l15]; bvv[ct]=bv[ct*16+l15]; }

  f32x4 acc[4][4];
  #pragma unroll
  for (int a=0;a<4;++a)
    #pragma unroll
    for (int b=0;b<4;++b) acc[a][b] = (f32x4){0.f,0.f,0.f,0.f};
  float sume[4] = {0.f,0.f,0.f,0.f};

  for (int tb=0; tb<2; ++tb){
    const int tbase = tok0 + tb*64;
    #pragma unroll
    for (int it=0; it<16; ++it){
      int row = it*4 + lg;
      float4 xv = *reinterpret_cast<const float4*>(&x[(size_t)(tbase+row)*64 + l15*4]);
      float s1 = xv.x+xv.y+xv.z+xv.w;
      float s2 = xv.x*xv.x + xv.y*xv.y + xv.z*xv.z + xv.w*xv.w;
      #pragma unroll
      for (int off=1; off<16; off<<=1){ s1 += __shfl_xor(s1,off,64); s2 += __shfl_xor(s2,off,64); }
      float mu = s1*(1.f/64.f);
      float rs = rsqrtf(s2*(1.f/64.f) - mu*mu + 1e-5f);
      uint2 pk = { pack2((xv.x-mu)*rs*g1v.x + be1v.x, (xv.y-mu)*rs*g1v.y + be1v.y),
                   pack2((xv.z-mu)*rs*g1v.z + be1v.z, (xv.w-mu)*rs*g1v.w + be1v.w) };
      *reinterpret_cast<uint2*>(&tile[row*64 + ((l15*4) ^ ((row&7)<<3))]) = pk;
    }
    bf16x8 aF[4][2];
    #pragma unroll
    for (int mt=0;mt<4;++mt){
      int row = mt*16+l15, sw=(row&7)<<3, ab=row*64;
      aF[mt][0] = __builtin_bit_cast(bf16x8, *reinterpret_cast<const u16x8*>(tile+ab+((     lg*8)^sw)));
      aF[mt][1] = __builtin_bit_cast(bf16x8, *reinterpret_cast<const u16x8*>(tile+ab+((32 + lg*8)^sw)));
    }
    #pragma unroll
    for (int half=0; half<2; ++half){
      #pragma unroll
      for (int m2=0;m2<2;++m2){
        const int mt = half*2+m2;
        #pragma unroll
        for (int ct=0;ct<4;++ct){
          f32x4 z = {0.f,0.f,0.f,0.f};
          z = mfma16(aF[mt][0], WkF[ct*2+0], z);
          z = mfma16(aF[mt][1], WkF[ct*2+1], z);
          float e0=__expf(z[0]+bkv[ct]), e1=__expf(z[1]+bkv[ct]);
          float e2=__expf(z[2]+bkv[ct]), e3=__expf(z[3]+bkv[ct]);
          sume[ct] += (e0+e1)+(e2+e3);
          const int c = ct*16+l15, sw = (c&7)<<3;
          const int cb = m2*16+lg*4;
          uint2 pe = { pack2(e0,e1), pack2(e2,e3) };
          *reinterpret_cast<uint2*>(&tile[c*64 + (cb ^ sw)]) = pe;
          f32x4 w = {0.f,0.f,0.f,0.f};
          w = mfma16(aF[mt][0], WvF[ct*2+0], w);
          w = mfma16(aF[mt][1], WvF[ct*2+1], w);
          uint2 pv = { pack2(w[0]+bvv[ct], w[1]+bvv[ct]), pack2(w[2]+bvv[ct], w[3]+bvv[ct]) };
          *reinterpret_cast<uint2*>(&tile[c*64 + ((32+cb) ^ sw)]) = pv;
        }
      }
      bf16x8 eA[4], vB[4];
      #pragma unroll
      for (int cm=0;cm<4;++cm){
        int row = cm*16+l15, sw=(row&7)<<3;
        eA[cm] = __builtin_bit_cast(bf16x8, *reinterpret_cast<const u16x8*>(tile + row*64 + ((     lg*8)^sw)));
        vB[cm] = __builtin_bit_cast(bf16x8, *reinterpret_cast<const u16x8*>(tile + row*64 + ((32 + lg*8)^sw)));
      }
      #pragma unroll
      for (int cm=0; cm<4; ++cm)
        #pragma unroll
        for (int jn=0; jn<4; ++jn)
          acc[cm][jn] = mfma16(eA[cm], vB[jn], acc[cm][jn]);
    }
  }
  #pragma unroll
  for (int ct=0; ct<4; ++ct){
    float s = sume[ct];
    s += __shfl_xor(s,16,64); s += __shfl_xor(s,32,64);
    if (lg==0) ssum_l[wid][ct*16+l15] = s;
  }
  #define CTX_RED(OP) \
    _Pragma("unroll") for (int cm=0;cm<4;++cm) \
    _Pragma("unroll") for (int jn=0;jn<4;++jn) \
    _Pragma("unroll") for (int r=0;r<4;++r) \
      ctx_l[(cm*16+lg*4+r)*68 + jn*16+l15] OP acc[cm][jn][r];
  if (wid==0){ CTX_RED(=) }  __syncthreads();
  if (wid==1){ CTX_RED(+=) } __syncthreads();
  if (wid==2){ CTX_RED(+=) } __syncthreads();
  if (wid==3){ CTX_RED(+=) } __syncthreads();
  #undef CTX_RED
  for (int i=t; i<4096; i+=256)
    g_part[(size_t)blockIdx.x*4096 + i] = ctx_l[(i>>6)*68 + (i&63)];
  if (t<64)
    g_sump[blockIdx.x*64 + t] = ssum_l[0][t]+ssum_l[1][t]+ssum_l[2][t]+ssum_l[3][t];
}

// ============ k15: reduce partials; ctxWr = (ctx_norm @ Wr^T) -> bf16 frags ============
__global__ __launch_bounds__(512) void k15_ctxwr(
  const float* __restrict__ g_part, const float* __restrict__ g_sump,
  const float* __restrict__ Wr, unsigned short* __restrict__ ctxWrF)
{
  __shared__ float sctx[4096];
  __shared__ float sWr[4096];
  __shared__ float sinv[64];
  const int b = blockIdx.x, t = threadIdx.x;
  if (t<64){
    float s=0.f;
    #pragma unroll 8
    for (int p=0;p<32;++p) s += g_sump[(b*32+p)*64 + t];
    sinv[t] = 1.f/s;
  }
  for (int idx=t; idx<4096; idx+=512){
    float s=0.f;
    #pragma unroll 8
    for (int p=0;p<32;++p) s += g_part[(size_t)(b*32+p)*4096 + idx];
    sctx[idx] = s;
  }
  __syncthreads();
  {
    int c = t>>3, d0 = (t&7)*8;
    float invc = sinv[c];
    #pragma unroll
    for (int dd=0; dd<8; ++dd){
      int d = d0+dd; float s = 0.f;
      #pragma unroll
      for (int v=0; v<64; ++v) s += sctx[c*64+v]*Wr[d*64+v];
      sWr[c*64+d] = s*invc;
    }
  }
  __syncthreads();
  {
    int f = t>>6, l = t&63, nt = f>>1, ks = f&1;
    u16x8 v;
    #pragma unroll
    for (int j=0;j<8;++j){
      int k = ks*32 + (l>>4)*8 + j;
      int n = nt*16 + (l&15);
      v[j] = f2bf(sWr[k*64+n]);
    }
    *reinterpret_cast<u16x8*>(ctxWrF + b*4096 + f*512 + l*8) = v;
  }
}

// ============ k2: LN1 + q-softmax + attn + residual + LN2 + W1 (nt2-outer phase B) ============
__global__ __launch_bounds__(256,2) void k2_attn_ffn1(
  const float* __restrict__ x,
  const float* __restrict__ g1, const float* __restrict__ be1,
  const float* __restrict__ bq, const float* __restrict__ br,
  const float* __restrict__ g2, const float* __restrict__ be2,
  const float* __restrict__ b1,
  const unsigned short* __restrict__ wf,
  const unsigned short* __restrict__ ctxWrF,
  unsigned short* __restrict__ g_txb, unsigned short* __restrict__ g_h)
{
  __shared__ unsigned short tiles[4][4096];
  const int t = threadIdx.x, wid = t>>6, l = t&63;
  const int l15 = l&15, lg = l>>4;
  unsigned short* tile = tiles[wid];
  const int tok0 = (blockIdx.x*4 + wid)*64;
  const int img  = blockIdx.x>>6;
  const int yrow = (tok0>>7)&127;
  const int xb   = tok0&127;
  const size_t hbase = ((size_t)(img*128 + yrow)*HPITCH + 1 + xb)*256;

  bf16x8 WqF[8], CWF[8];
  #pragma unroll
  for (int f=0; f<8; ++f){
    WqF[f] = ldfrag_g(wf + 4096 + f*512 + l*8);
    CWF[f] = ldfrag_g(ctxWrF + img*4096 + f*512 + l*8);
  }
  float4 g1v  = *reinterpret_cast<const float4*>(&g1[l15*4]);
  float4 be1v = *reinterpret_cast<const float4*>(&be1[l15*4]);
  float bqv[4], brv[4], g2v[4], be2v[4];
  #pragma unroll
  for (int nt=0; nt<4; ++nt){
    bqv[nt]=bq[nt*16+l15]; brv[nt]=br[nt*16+l15];
    g2v[nt]=g2[nt*16+l15]; be2v[nt]=be2[nt*16+l15];
  }
  float b1v[16];
  #pragma unroll
  for (int i=0;i<16;++i) b1v[i]=b1[i*16+l15];

  // ---- LN1 -> swizzled bf16 tile ----
  #pragma unroll
  for (int it=0; it<16; ++it){
    int row = it*4 + lg;
    float4 xv = *reinterpret_cast<const float4*>(&x[(size_t)(tok0+row)*64 + l15*4]);
    float s1 = xv.x+xv.y+xv.z+xv.w;
    float s2 = xv.x*xv.x + xv.y*xv.y + xv.z*xv.z + xv.w*xv.w;
    #pragma unroll
    for (int off=1; off<16; off<<=1){ s1 += __shfl_xor(s1,off,64); s2 += __shfl_xor(s2,off,64); }
    float mu = s1*(1.f/64.f);
    float rs = rsqrtf(s2*(1.f/64.f) - mu*mu + 1e-5f);
    uint2 pk = { pack2((xv.x-mu)*rs*g1v.x + be1v.x, (xv.y-mu)*rs*g1v.y + be1v.y),
                 pack2((xv.z-mu)*rs*g1v.z + be1v.z, (xv.w-mu)*rs*g1v.w + be1v.w) };
    *reinterpret_cast<uint2*>(&tile[row*64 + ((l15*4) ^ ((row&7)<<3))]) = pk;
  }

  // ---- phase A: per m-tile attn chain; leaves n2 in the tile ----
  for (int mt=0; mt<4; ++mt){
    const int arow = mt*16 + l15;
    const int asw  = (arow&7)<<3;
    const int abase= arow*64;
    bf16x8 a0 = __builtin_bit_cast(bf16x8, *reinterpret_cast<const u16x8*>(tile + abase + ((     lg*8) ^ asw)));
    bf16x8 a1 = __builtin_bit_cast(bf16x8, *reinterpret_cast<const u16x8*>(tile + abase + ((32 + lg*8) ^ asw)));
    f32x4 qa[4];
    #pragma unroll
    for (int nt=0; nt<4; ++nt){
      f32x4 z = {0.f,0.f,0.f,0.f};
      z = mfma16(a0, WqF[nt*2+0], z);
      z = mfma16(a1, WqF[nt*2+1], z);
      qa[nt] = z;
    }
    #pragma unroll
    for (int nt=0; nt<4; ++nt)
      #pragma unroll
      for (int r=0; r<4; ++r) qa[nt][r] += bqv[nt];
    float mx[4];
    #pragma unroll
    for (int r=0;r<4;++r) mx[r] = fmaxf(fmaxf(qa[0][r],qa[1][r]), fmaxf(qa[2][r],qa[3][r]));
    #pragma unroll
    for (int off=1; off<16; off<<=1)
      #pragma unroll
      for (int r=0;r<4;++r) mx[r] = fmaxf(mx[r], __shfl_xor(mx[r], off, 64));
    float sm[4] = {0.f,0.f,0.f,0.f};
    #pragma unroll
    for (int nt=0;nt<4;++nt)
      #pragma unroll
      for (int r=0;r<4;++r){ float e = __expf(qa[nt][r]-mx[r]); qa[nt][r]=e; sm[r]+=e; }
    #pragma unroll
    for (int off=1; off<16; off<<=1)
      #pragma unroll
      for (int r=0;r<4;++r) sm[r] += __shfl_xor(sm[r], off, 64);
    float inv[4];
    #pragma unroll
    for (int r=0;r<4;++r) inv[r] = 1.f/sm[r];
    #pragma unroll
    for (int nt=0;nt<4;++nt)
      #pragma unroll
      for (int r=0;r<4;++r){
        int row = mt*16 + lg*4 + r, col = nt*16 + l15;
        tile[row*64 + (col ^ ((row&7)<<3))] = f2bf(qa[nt][r]*inv[r]);
      }
    bf16x8 p0 = __builtin_bit_cast(bf16x8, *reinterpret_cast<const u16x8*>(tile + abase + ((     lg*8) ^ asw)));
    bf16x8 p1 = __builtin_bit_cast(bf16x8, *reinterpret_cast<const u16x8*>(tile + abase + ((32 + lg*8) ^ asw)));
    f32x4 ao[4];
    #pragma unroll
    for (int nt=0; nt<4; ++nt){
      f32x4 z = {0.f,0.f,0.f,0.f};
      z = mfma16(p0, CWF[nt*2+0], z);
      z = mfma16(p1, CWF[nt*2+1], z);
      ao[nt] = z;
    }
    float txv[4][4];
    float s1v[4] = {0.f,0.f,0.f,0.f}, s2v[4] = {0.f,0.f,0.f,0.f};
    #pragma unroll
    for (int nt=0;nt<4;++nt)
      #pragma unroll
      for (int r=0;r<4;++r){
        size_t row = (size_t)(tok0 + mt*16 + lg*4 + r);
        float v = ao[nt][r] + brv[nt] + x[row*64 + nt*16+l15];
        g_txb[row*64 + nt*16+l15] = f2bf(v);
        txv[nt][r] = v; s1v[r] += v; s2v[r] += v*v;
      }
    #pragma unroll
    for (int off=1; off<16; off<<=1)
      #pragma unroll
      for (int r=0;r<4;++r){ s1v[r] += __shfl_xor(s1v[r], off, 64); s2v[r] += __shfl_xor(s2v[r], off, 64); }
    #pragma unroll
    for (int r=0;r<4;++r){
      float mu2 = s1v[r]*(1.f/64.f);
      float rs  = rsqrtf(s2v[r]*(1.f/64.f) - mu2*mu2 + 1e-5f);
      s1v[r] = mu2; s2v[r] = rs;
    }
    #pragma unroll
    for (int nt=0;nt<4;++nt)
      #pragma unroll
      for (int r=0;r<4;++r){
        int row = mt*16 + lg*4 + r, col = nt*16 + l15;
        float n2 = (txv[nt][r]-s1v[r])*s2v[r]*g2v[nt] + be2v[nt];
        tile[row*64 + (col ^ ((row&7)<<3))] = f2bf(n2);
      }
  }

  // ---- phase B: h = n2 @ W1^T + b1 (nt2 outer: each W1 frag loaded ONCE) ----
  #pragma unroll 2
  for (int nt2=0; nt2<16; ++nt2){
    bf16x8 w0 = ldfrag_g(wf + 16384 + (nt2*2+0)*512 + l*8);
    bf16x8 w1 = ldfrag_g(wf + 16384 + (nt2*2+1)*512 + l*8);
    float bb = b1v[nt2];
    #pragma unroll
    for (int mt=0; mt<4; ++mt){
      const int arow = mt*16 + l15;
      const int asw  = (arow&7)<<3;
      const int abase= arow*64;
      bf16x8 n20 = __builtin_bit_cast(bf16x8, *reinterpret_cast<const u16x8*>(tile + abase + ((     lg*8) ^ asw)));
      bf16x8 n21 = __builtin_bit_cast(bf16x8, *reinterpret_cast<const u16x8*>(tile + abase + ((32 + lg*8) ^ asw)));
      f32x4 h = {bb,bb,bb,bb};
      h = mfma16(n20, w0, h);
      h = mfma16(n21, w1, h);
      #pragma unroll
      for (int r=0;r<4;++r)
        g_h[hbase + (size_t)(mt*16+lg*4+r)*256 + nt2*16 + l15] = f2bf(h[r]);
    }
  }
}

// ============ k3: depthwise conv3x3 + GELU + W2 (prefetched, packed-f32 conv) ============
__global__ __launch_bounds__(256,2) void k3_conv_ffn2(
  const unsigned short* __restrict__ g_h,
  const unsigned short* __restrict__ zrow,
  const float* __restrict__ dwp, const float* __restrict__ dwb,
  const float* __restrict__ b2,
  const unsigned short* __restrict__ wf,
  const unsigned short* __restrict__ g_txb, float* __restrict__ out)
{
  __shared__ unsigned short tiles[4][4096];
  const int t = threadIdx.x, wid = t>>6, l = t&63;
  const int l15 = l&15, lg = l>>4;
  unsigned short* tile = tiles[wid];
  const int blk = (blockIdx.x & 7)*128 + (blockIdx.x >> 3);   // XCD-chunked remap
  const int strip = blk*4 + wid;
  const int tok0 = strip*64;
  const int img  = tok0>>14;
  const int y    = (tok0>>7)&127;
  const int x0   = tok0&127;
  const bool okm = (y>0), okp = (y<127);
  const int p    = lg;
  const int ch   = l15;

  f32x4 oacc[4][4];   // [ntc][mtk]
  #pragma unroll
  for (int a=0;a<4;++a)
    #pragma unroll
    for (int b=0;b<4;++b) oacc[a][b] = (f32x4){0.f,0.f,0.f,0.f};

  const size_t base = ((size_t)(img*128+y)*HPITCH + x0 + p*16)*256;

  // gelu constants with log2(e) folded in: exp(v*(c0 + c1*v^2)) = exp2(v*(C0 + C1*v^2))
  const f32x4 kC0 = {-2.3022082f,-2.3022082f,-2.3022082f,-2.3022082f};
  const f32x4 kC1 = {-0.1029432f,-0.1029432f,-0.1029432f,-0.1029432f};
  const f32x4 kOne = {1.f,1.f,1.f,1.f};

  for (int i=0;i<4;++i){
    const int f0 = i*64 + ch*4;
    // taps already transposed: dwp[(i*16+ch)*36 + j*4 + c]
    f32x4 cw4[9];
    #pragma unroll
    for (int j=0;j<9;++j)
      cw4[j] = *reinterpret_cast<const f32x4*>(&dwp[(i*16+ch)*36 + j*4]);
    float4 cb4 = *reinterpret_cast<const float4*>(&dwb[f0]);
    f32x4 cbv = {cb4.x, cb4.y, cb4.z, cb4.w};

    const unsigned short* rB = g_h + base + f0;
    const unsigned short* rA = okm ? (rB - HROW) : (zrow + f0);
    const unsigned short* rC = okp ? (rB + HROW) : (zrow + f0);

    // software-prefetch ring: 18 x-positions (x-1 .. x+16), loads issued 4
    // iterations before use so LLC latency hides under the conv VALU work.
    uint2 qA[18], qB[18], qC[18];
    f32x4 fA[18], fB[18], fC[18];
    #pragma unroll
    for (int o=0;o<6;++o){
      qA[o] = *reinterpret_cast<const uint2*>(rA + o*256);
      qB[o] = *reinterpret_cast<const uint2*>(rB + o*256);
      qC[o] = *reinterpret_cast<const uint2*>(rC + o*256);
    }
    fA[0]=bfcvt4(qA[0]); fB[0]=bfcvt4(qB[0]); fC[0]=bfcvt4(qC[0]);
    fA[1]=bfcvt4(qA[1]); fB[1]=bfcvt4(qB[1]); fC[1]=bfcvt4(qC[1]);
    #pragma unroll
    for (int s=0;s<16;++s){
      if (s<12){
        qA[s+6] = *reinterpret_cast<const uint2*>(rA + (s+6)*256);
        qB[s+6] = *reinterpret_cast<const uint2*>(rB + (s+6)*256);
        qC[s+6] = *reinterpret_cast<const uint2*>(rC + (s+6)*256);
      }
      fA[s+2]=bfcvt4(qA[s+2]); fB[s+2]=bfcvt4(qB[s+2]); fC[s+2]=bfcvt4(qC[s+2]);
      f32x4 a = cbv;
      a += cw4[0]*fA[s]; a += cw4[1]*fA[s+1]; a += cw4[2]*fA[s+2];
      a += cw4[3]*fB[s]; a += cw4[4]*fB[s+1]; a += cw4[5]*fB[s+2];
      a += cw4[6]*fC[s]; a += cw4[7]*fC[s+1]; a += cw4[8]*fC[s+2];
      // gelu (tanh-free sigmoid approx, log2e folded): g = a / (1 + exp2(a*(C0+C1*a^2)))
      f32x4 u = a*a;
      f32x4 w = u*kC1 + kC0;
      f32x4 arg = a*w;
      f32x4 e;
      e[0]=__builtin_amdgcn_exp2f(arg[0]); e[1]=__builtin_amdgcn_exp2f(arg[1]);
      e[2]=__builtin_amdgcn_exp2f(arg[2]); e[3]=__builtin_amdgcn_exp2f(arg[3]);
      f32x4 den = e + kOne;
      f32x4 rc;
      rc[0]=__builtin_amdgcn_rcpf(den[0]); rc[1]=__builtin_amdgcn_rcpf(den[1]);
      rc[2]=__builtin_amdgcn_rcpf(den[2]); rc[3]=__builtin_amdgcn_rcpf(den[3]);
      f32x4 g = a*rc;
      unsigned lo, hi;
      asm("v_cvt_pk_bf16_f32 %0, %1, %2" : "=v"(lo) : "v"(g[0]), "v"(g[1]));
      asm("v_cvt_pk_bf16_f32 %0, %1, %2" : "=v"(hi) : "v"(g[2]), "v"(g[3]));
      uint2 pk = { lo, hi };
      int row = p*16 + s;
      *reinterpret_cast<uint2*>(&tile[row*64 + ((ch*4) ^ ((row&7)<<3))]) = pk;
    }
    bf16x8 W2F[8];
    #pragma unroll
    for (int q=0;q<8;++q){
      int ntc = q>>1, cks = q&1;
      W2F[q] = ldfrag_g(wf + 32768 + (ntc*8 + i*2 + cks)*512 + l*8);
    }
    #pragma unroll
    for (int mtk=0; mtk<4; ++mtk){
      int row = mtk*16 + l15;
      int sw = (row&7)<<3;
      bf16x8 fb0 = __builtin_bit_cast(bf16x8, *reinterpret_cast<const u16x8*>(tile + row*64 + ((     lg*8) ^ sw)));
      bf16x8 fb1 = __builtin_bit_cast(bf16x8, *reinterpret_cast<const u16x8*>(tile + row*64 + ((32 + lg*8) ^ sw)));
      #pragma unroll
      for (int ntc=0;ntc<4;++ntc){
        oacc[ntc][mtk] = mfma16(W2F[ntc*2+0], fb0, oacc[ntc][mtk]);
        oacc[ntc][mtk] = mfma16(W2F[ntc*2+1], fb1, oacc[ntc][mtk]);
      }
    }
  }
  // ---- vector epilogue: out-ch on regs (consecutive), token = l15 ----
  #pragma unroll
  for (int mtk=0;mtk<4;++mtk){
    const size_t rowoff = (size_t)(tok0 + mtk*16 + l15)*64;
    #pragma unroll
    for (int ntc=0;ntc<4;++ntc){
      float4 b2q = *reinterpret_cast<const float4*>(&b2[ntc*16 + lg*4]);
      u16x4v tq = *reinterpret_cast<const u16x4v*>(&g_txb[rowoff + ntc*16 + lg*4]);
      float4 o;
      o.x = oacc[ntc][mtk][0] + b2q.x + bf2f(tq[0]);
      o.y = oacc[ntc][mtk][1] + b2q.y + bf2f(tq[1]);
      o.z = oacc[ntc][mtk][2] + b2q.z + bf2f(tq[2]);
      o.w = oacc[ntc][mtk][3] + b2q.w + bf2f(tq[3]);
      *reinterpret_cast<float4*>(&out[rowoff + ntc*16 + lg*4]) = o;
    }
  }
}

extern "C" void kernel_launch(void* const* d_in, const int* in_sizes, int n_in,
                              void* d_out, int out_size, void* d_ws, size_t ws_size,
                              hipStream_t stream)
{
  const float* x  =(const float*)d_in[0];
  const float* g1 =(const float*)d_in[3];
  const float* be1=(const float*)d_in[4];
  const float* Wk =(const float*)d_in[5];
  const float* bk =(const float*)d_in[6];
  const float* Wq =(const float*)d_in[7];
  const float* bq =(const float*)d_in[8];
  const float* Wv =(const float*)d_in[9];
  const float* bv =(const float*)d_in[10];
  const float* Wr =(const float*)d_in[11];
  const float* br =(const float*)d_in[12];
  const float* g2 =(const float*)d_in[13];
  const float* be2=(const float*)d_in[14];
  const float* W1 =(const float*)d_in[15];
  const float* b1 =(const float*)d_in[16];
  const float* dww=(const float*)d_in[17];
  const float* dwb=(const float*)d_in[18];
  const float* W2 =(const float*)d_in[19];
  const float* b2 =(const float*)d_in[20];
  float* outp = (float*)d_out;
  char* ws = (char*)d_ws;

  unsigned short* wfb    = (unsigned short*)ws;                 // 96KB
  unsigned short* ctxWrF = (unsigned short*)(ws + 98304);       // 128KB
  float* g_sump = (float*)(ws + 229376);                        // 128KB
  float* g_part = (float*)(ws + 393216);                        // 8MB
  unsigned short* g_txb = (unsigned short*)(ws + 16777216);     // 32MB bf16
  unsigned short* g_h   = (unsigned short*)(ws + 50331648);     // 136.3MB padded bf16
  unsigned short* zr    = (unsigned short*)(ws + 186646528);    // 65KB zero row
  float* dwp            = (float*)(ws + 186712064);             // 12KB repacked taps

  hipLaunchKernelGGL(k0_wfrag, dim3(97), dim3(64), 0, stream, Wk, Wq, Wv, Wr, W1, W2, dww, dwp, wfb);
  hipLaunchKernelGGL(zhalo, dim3(2113), dim3(256), 0, stream, (unsigned*)g_h, (unsigned*)zr);
  hipLaunchKernelGGL(k1_ctx, dim3(512), dim3(256), 0, stream, x, g1, be1, bk, bv, wfb, g_part, g_sump);
  hipLaunchKernelGGL(k15_ctxwr, dim3(16), dim3(512), 0, stream, g_part, g_sump, Wr, ctxWrF);
  hipLaunchKernelGGL(k2_attn_ffn1, dim3(1024), dim3(256), 0, stream,
                     x, g1, be1, bq, br, g2, be2, b1, wfb, ctxWrF, g_txb, g_h);
  hipLaunchKernelGGL(k3_conv_ffn2, dim3(1024), dim3(256), 0, stream,
                     g_h, zr, dwp, dwb, b2, wfb, g_txb, outp);
}